// Round 6
// baseline (49.990 us; speedup 1.0000x reference)
//
#include <hip/hip_runtime.h>
#include <math.h>

#define NBATCH 4
#define NPTS   8192
#define TPB    512
#define NWAVE  (TPB / 64)                 // 8 waves
#define QPT    16                         // queries per lane
#define QPB    (64 * QPT)                 // 1024 queries per block
#define QTILES (NPTS / QPB)               // 8 query tiles
#define PSPLIT 4                          // point-set split across blocks
#define PPB    (NPTS / PSPLIT)            // 2048 points staged per block
#define SLICE  (PPB / NWAVE)              // 256 points per wave
#define NBLK   (2 * NBATCH * QTILES * PSPLIT)  // 256 blocks = 1 per CU
#define NTILEB (2 * NBATCH * QTILES)      // 64 (dir,b,tile) groups

typedef float v2f __attribute__((ext_vector_type(2)));
typedef float v4f __attribute__((ext_vector_type(4)));

// Forced 3-input min (fminf chains don't fuse without fast-math; inputs
// here are finite so v_min3_f32 semantics are safe).
__device__ __forceinline__ float min3a(float m, float a, float b) {
    float r;
    asm("v_min3_f32 %0, %1, %2, %3" : "=v"(r) : "v"(m), "v"(a), "v"(b));
    return r;
}

// Block = (dir, batch, 1024-query tile, quarter of the point set).
// 2048 points staged in LDS SoA (-2x,-2y,-2z,||p||^2), 32 KiB. Wave w scans
// its 256-point slice; all 64 lanes read the same address (broadcast).
// Queries held as v2f SPLATS (round-3 pattern: this is what makes LLVM emit
// v_pk_fma_f32; no shufflevector anywhere). Inner math per (2 points, 1
// query): 3 v_pk_fma_f32 + 1 v_min3_f32 = 2.0 VALU instr/pair. qn is added
// after the min. __launch_bounds__(512,2) -> 256-VGPR cap, no spill for the
// ~96 splat regs. 1 block/CU; DS traffic = 2048 ds_read_b128/CU.
__global__ __launch_bounds__(TPB, 2) void chamfer_main(
    const float* __restrict__ xyz1,
    const float* __restrict__ xyz2,
    float* __restrict__ ws_part)
{
    __shared__ float sx[PPB] __attribute__((aligned(16)));
    __shared__ float sy[PPB] __attribute__((aligned(16)));
    __shared__ float sz[PPB] __attribute__((aligned(16)));
    __shared__ float sw[PPB] __attribute__((aligned(16)));
    __shared__ float part[NWAVE][QPB];    // 32 KiB slice partial mins

    const int bid  = blockIdx.x;
    const int ps   = bid & (PSPLIT - 1);
    const int r1   = bid >> 2;
    const int tile = r1 & (QTILES - 1);
    const int r2   = r1 >> 3;
    const int b    = r2 & (NBATCH - 1);
    const int dir  = r2 >> 2;             // 0: q=xyz1,r=xyz2; 1: swapped

    const float* q  = (dir == 0 ? xyz1 : xyz2) + (size_t)b * NPTS * 3;
    const float* rp = (dir == 0 ? xyz2 : xyz1) + (size_t)b * NPTS * 3
                      + (size_t)ps * PPB * 3;

    for (int i = threadIdx.x; i < PPB; i += TPB) {
        float x = rp[3 * i + 0], y = rp[3 * i + 1], z = rp[3 * i + 2];
        sx[i] = -2.0f * x;
        sy[i] = -2.0f * y;
        sz[i] = -2.0f * z;
        sw[i] = x * x + y * y + z * z;
    }
    __syncthreads();

    const int lane = threadIdx.x & 63;
    const int w    = threadIdx.x >> 6;
    const int q0   = tile * QPB + lane * QPT;

    v2f qxv[QPT], qyv[QPT], qzv[QPT];
    float m[QPT];
    #pragma unroll
    for (int k = 0; k < QPT; ++k) {
        const float Qx = q[3 * (q0 + k) + 0];
        const float Qy = q[3 * (q0 + k) + 1];
        const float Qz = q[3 * (q0 + k) + 2];
        qxv[k] = (v2f){ Qx, Qx };
        qyv[k] = (v2f){ Qy, Qy };
        qzv[k] = (v2f){ Qz, Qz };
        m[k]   = INFINITY;
    }

    const int base = w * SLICE;
    #pragma unroll 1
    for (int j = 0; j < SLICE; j += 8) {
        v4f X0 = *(const v4f*)&sx[base + j];
        v4f X1 = *(const v4f*)&sx[base + j + 4];
        v4f Y0 = *(const v4f*)&sy[base + j];
        v4f Y1 = *(const v4f*)&sy[base + j + 4];
        v4f Z0 = *(const v4f*)&sz[base + j];
        v4f Z1 = *(const v4f*)&sz[base + j + 4];
        v4f W0 = *(const v4f*)&sw[base + j];
        v4f W1 = *(const v4f*)&sw[base + j + 4];

        v2f Px[4] = { X0.lo, X0.hi, X1.lo, X1.hi };
        v2f Py[4] = { Y0.lo, Y0.hi, Y1.lo, Y1.hi };
        v2f Pz[4] = { Z0.lo, Z0.hi, Z1.lo, Z1.hi };
        v2f Pw[4] = { W0.lo, W0.hi, W1.lo, W1.hi };

        #pragma unroll
        for (int g = 0; g < 4; ++g) {
            #pragma unroll
            for (int k = 0; k < QPT; ++k) {
                v2f d = __builtin_elementwise_fma(qxv[k], Px[g],
                        __builtin_elementwise_fma(qyv[k], Py[g],
                        __builtin_elementwise_fma(qzv[k], Pz[g], Pw[g])));
                m[k] = min3a(m[k], d.x, d.y);
            }
        }
    }

    // Swizzled store (stride-64B pattern would be a wide bank conflict).
    #pragma unroll
    for (int k = 0; k < QPT; ++k) {
        const int col = lane * QPT + ((k + lane) & (QPT - 1));
        part[w][col] = m[k];
    }
    __syncthreads();

    // Combine the 8 wave-slices per query, add qn, write block partial.
    for (int ql = threadIdx.x; ql < QPB; ql += TPB) {
        const int l   = ql >> 4;
        const int col = (ql & ~(QPT - 1)) | ((ql + l) & (QPT - 1));
        float mv = part[0][col];
        #pragma unroll
        for (int s = 1; s < NWAVE; ++s) mv = fminf(mv, part[s][col]);
        const int qi = tile * QPB + ql;
        const float Qx = q[3 * qi + 0], Qy = q[3 * qi + 1], Qz = q[3 * qi + 2];
        ws_part[(size_t)bid * QPB + ql] = (Qx * Qx + Qy * Qy + Qz * Qz) + mv;
    }
}

// 64 blocks = one per (dir,b,tile): min over PSPLIT partials, threshold,
// per-tile double sum -> tile_sums.
__global__ __launch_bounds__(256) void chamfer_finalize1(
    const float* __restrict__ ws_part,
    const float* __restrict__ thp,
    double* __restrict__ tile_sums)
{
    __shared__ double wsum[4];
    const int t = blockIdx.x;             // t = ((dir*4+b)*8+tile)
    const float th = *thp;
    const size_t gb = (size_t)t * PSPLIT;
    double acc = 0.0;
    for (int ql = threadIdx.x; ql < QPB; ql += 256) {
        float mv = ws_part[(gb + 0) * QPB + ql];
        #pragma unroll
        for (int s = 1; s < PSPLIT; ++s)
            mv = fminf(mv, ws_part[(gb + s) * QPB + ql]);
        acc += (mv <= th) ? 0.0 : (double)mv;
    }
    for (int off = 32; off > 0; off >>= 1)
        acc += __shfl_down(acc, off, 64);
    const int lane = threadIdx.x & 63;
    const int w    = threadIdx.x >> 6;
    if (lane == 0) wsum[w] = acc;
    __syncthreads();
    if (threadIdx.x == 0) {
        tile_sums[t] = wsum[0] + wsum[1] + wsum[2] + wsum[3];
    }
}

__global__ void chamfer_finalize2(const double* __restrict__ tile_sums,
                                  float* __restrict__ out)
{
    const int b = threadIdx.x;
    if (b < NBATCH) {
        double s = 0.0;
        for (int dir = 0; dir < 2; ++dir)
            for (int t = 0; t < QTILES; ++t)
                s += tile_sums[(dir * NBATCH + b) * QTILES + t];
        out[b] = (float)(s / (double)NPTS);   // mean(d1)+mean(d2), N == M
    }
}

extern "C" void kernel_launch(void* const* d_in, const int* in_sizes, int n_in,
                              void* d_out, int out_size, void* d_ws, size_t ws_size,
                              hipStream_t stream) {
    const float* xyz1 = (const float*)d_in[0];
    const float* xyz2 = (const float*)d_in[1];
    const float* thp  = (const float*)d_in[2];
    float* out        = (float*)d_out;
    float* ws_part    = (float*)d_ws;                       // 256*1024*4 = 1 MiB
    double* tile_sums = (double*)(ws_part + NBLK * QPB);    // + 64*8 B

    chamfer_main<<<NBLK, TPB, 0, stream>>>(xyz1, xyz2, ws_part);
    chamfer_finalize1<<<NTILEB, 256, 0, stream>>>(ws_part, thp, tile_sums);
    chamfer_finalize2<<<1, 64, 0, stream>>>(tile_sums, out);
}